// Round 3
// baseline (176.108 us; speedup 1.0000x reference)
//
#include <hip/hip_runtime.h>

typedef float f32x4 __attribute__((ext_vector_type(4)));
typedef __bf16 bf16x8 __attribute__((ext_vector_type(8)));
typedef unsigned short u16x8 __attribute__((ext_vector_type(8)));

#define D_DIM 128
#define NSPLIT 32
#define BJ 64
#define SCALE  1.2011224087864498f   // sqrt(log2(e)): both operands scaled -> acc = log2e * sim
#define LN2    0.6931471805599453f
#define E1F    2.7182818284590452f

// fp32 -> bf16 round-to-nearest-even
static __device__ __forceinline__ unsigned short f2bf(float f) {
    unsigned u = __float_as_uint(f);
    u += 0x7fffu + ((u >> 16) & 1u);
    return (unsigned short)(u >> 16);
}

static __device__ __forceinline__ void gload_lds16(const unsigned short* gsrc, void* lds_dst) {
    auto gp = (const __attribute__((address_space(1))) unsigned int*)gsrc;
    auto lp = (__attribute__((address_space(3))) unsigned int*)(unsigned int)(unsigned long long)lds_dst;
    __builtin_amdgcn_global_load_lds(gp, lp, 16, 0, 0);
}

// ---------------------------------------------------------------------------
// prep: L2-normalize rows (scaled by sqrt(log2e)), store bf16 A.
// Per-block (64 rows): class-colsum partials Cpart[blk][256] (plain stores),
// n0part[blk], zero S1 rows, block 0 zeroes the finale counter.
// 16-lane groups: 4 rows per wave in parallel, 4 iterations.
__global__ __launch_bounds__(256) void prep_kernel(const float* __restrict__ X,
                                                   const int* __restrict__ labels,
                                                   unsigned short* __restrict__ A,
                                                   float* __restrict__ Cpart,
                                                   int* __restrict__ n0part,
                                                   float* __restrict__ S1,
                                                   int* __restrict__ counter) {
    int tid = threadIdx.x, wave = tid >> 6, lane = tid & 63;
    int g = lane >> 4, s = lane & 15;
    int row0 = blockIdx.x * 64;

    float c0[8], c1[8];
    #pragma unroll
    for (int e = 0; e < 8; ++e) { c0[e] = 0.f; c1[e] = 0.f; }

    #pragma unroll
    for (int it = 0; it < 4; ++it) {
        int row = row0 + wave * 16 + it * 4 + g;
        const float4* xp = reinterpret_cast<const float4*>(X + (size_t)row * D_DIM + s * 8);
        float4 xa = xp[0], xb = xp[1];
        float ss = xa.x*xa.x + xa.y*xa.y + xa.z*xa.z + xa.w*xa.w
                 + xb.x*xb.x + xb.y*xb.y + xb.z*xb.z + xb.w*xb.w;
        ss += __shfl_xor(ss, 1); ss += __shfl_xor(ss, 2);
        ss += __shfl_xor(ss, 4); ss += __shfl_xor(ss, 8);
        float rn = rsqrtf(ss) * SCALE;
        float v[8] = { xa.x*rn, xa.y*rn, xa.z*rn, xa.w*rn,
                       xb.x*rn, xb.y*rn, xb.z*rn, xb.w*rn };
        u16x8 o;
        #pragma unroll
        for (int e = 0; e < 8; ++e) o[e] = f2bf(v[e]);
        *reinterpret_cast<u16x8*>(A + (size_t)row * D_DIM + s * 8) = o;
        bool is0 = (labels[row] == 0);
        #pragma unroll
        for (int e = 0; e < 8; ++e) {
            c0[e] += is0 ? v[e] : 0.f;
            c1[e] += is0 ? 0.f : v[e];
        }
    }

    __shared__ float CL[256];
    CL[tid] = 0.f;
    __syncthreads();
    #pragma unroll
    for (int e = 0; e < 8; ++e) {
        atomicAdd(&CL[s * 8 + e],       c0[e]);
        atomicAdd(&CL[128 + s * 8 + e], c1[e]);
    }
    __syncthreads();
    Cpart[(size_t)blockIdx.x * 256 + tid] = CL[tid];

    if (wave == 0) {
        int is0 = (labels[row0 + lane] == 0) ? 1 : 0;
        unsigned long long b = __ballot(is0);
        if (lane == 0) n0part[blockIdx.x] = (int)__popcll(b);
    }
    if (tid < 64) S1[row0 + tid] = 0.f;
    if (blockIdx.x == 0 && tid == 0) *counter = 0;
}

// ---------------------------------------------------------------------------
// main: S1[i] += sum_{j in split} exp(sim_ij), double-buffered LDS staging.
// Last block (atomic counter) computes the loss:
//   loss = ((n0-1)*L0 - (||C0||^2 - n0))/n0 + (n1-1)*L1 - (||C1||^2 - n1)
//   with Lc = sum_{i in c} log(S1_i - e).
__global__ __launch_bounds__(256, 3) void main_kernel(const unsigned short* __restrict__ A,
                                                      const int* __restrict__ labels,
                                                      const float* __restrict__ Cpart,
                                                      const int* __restrict__ n0part,
                                                      float* __restrict__ S1,
                                                      int* __restrict__ counter,
                                                      float* __restrict__ out,
                                                      int N, int nprep) {
    __shared__ unsigned short Bs[2][8192];   // 2 x 16 KB, [col][k] XOR-swizzled
    int tid = threadIdx.x, wave = tid >> 6, lane = tid & 63;
    int l15 = lane & 15, lhi = lane >> 4;
    int m0 = blockIdx.x * 256 + wave * 64;
    int split = blockIdx.y;
    int jlen = N / NSPLIT;
    int j0 = split * jlen;
    const int TILES = jlen / BJ;             // 4 at N=8192

    // A fragments: rows m0 + ms*16 + l15, k = kb*32 + lhi*8 .. +7
    bf16x8 af[4][4];
    const unsigned short* abase = A + (size_t)(m0 + l15) * D_DIM + lhi * 8;
    #pragma unroll
    for (int ms = 0; ms < 4; ++ms)
        #pragma unroll
        for (int kb = 0; kb < 4; ++kb)
            af[ms][kb] = *reinterpret_cast<const bf16x8*>(abase + (size_t)ms * 16 * D_DIM + kb * 32);

    float s1[4][4];
    #pragma unroll
    for (int ms = 0; ms < 4; ++ms)
        #pragma unroll
        for (int r = 0; r < 4; ++r) s1[ms][r] = 0.f;

    int sw = (l15 & 7) << 4;

    auto stage = [&](int buf, int jt) {
        #pragma unroll
        for (int it = 0; it < 4; ++it) {
            int Lb  = it * 4096 + tid * 16;
            int col = Lb >> 8;
            int off = (Lb & 255) ^ ((col & 7) << 4);
            gload_lds16(A + (size_t)(jt + col) * D_DIM + (off >> 1),
                        (char*)(&Bs[0][0]) + buf * 16384 + it * 4096 + wave * 1024);
        }
    };

    stage(0, j0);
    __syncthreads();
    int buf = 0;
    for (int t = 0; t < TILES; ++t) {
        if (t + 1 < TILES) stage(buf ^ 1, j0 + (t + 1) * BJ);   // prefetch next tile
        const char* BsB = (const char*)(&Bs[0][0]) + buf * 16384;
        #pragma unroll
        for (int cs = 0; cs < 4; ++cs) {
            int colb = (cs * 16 + l15) * 256;
            bf16x8 bfr[4];
            #pragma unroll
            for (int kb = 0; kb < 4; ++kb)
                bfr[kb] = *reinterpret_cast<const bf16x8*>(BsB + colb + ((kb * 64 + lhi * 16) ^ sw));
            f32x4 acc[4] = {{0,0,0,0},{0,0,0,0},{0,0,0,0},{0,0,0,0}};
            #pragma unroll
            for (int kb = 0; kb < 4; ++kb)
                #pragma unroll
                for (int ms = 0; ms < 4; ++ms)
                    acc[ms] = __builtin_amdgcn_mfma_f32_16x16x32_bf16(af[ms][kb], bfr[kb], acc[ms], 0, 0, 0);
            #pragma unroll
            for (int ms = 0; ms < 4; ++ms)
                #pragma unroll
                for (int r = 0; r < 4; ++r)
                    s1[ms][r] += __builtin_amdgcn_exp2f(acc[ms][r]);
        }
        __syncthreads();   // drains prefetch vmcnt + all waves done reading buf
        buf ^= 1;
    }

    // reduce over the 16 l15-lanes holding the same rows
    #pragma unroll
    for (int m = 1; m < 16; m <<= 1)
        #pragma unroll
        for (int ms = 0; ms < 4; ++ms)
            #pragma unroll
            for (int r = 0; r < 4; ++r)
                s1[ms][r] += __shfl_xor(s1[ms][r], m);
    if (l15 == 0) {
        #pragma unroll
        for (int ms = 0; ms < 4; ++ms)
            #pragma unroll
            for (int r = 0; r < 4; ++r)
                atomicAdd(&S1[m0 + ms * 16 + lhi * 4 + r], s1[ms][r]);
    }

    // ---- last-block finale ----
    __shared__ int isLast;
    __syncthreads();
    if (tid == 0) {
        __threadfence();
        int old = atomicAdd(counter, 1);
        isLast = (old == (int)(gridDim.x * gridDim.y) - 1) ? 1 : 0;
    }
    __syncthreads();
    if (isLast) {
        // C column sums -> ||C0||^2, ||C1||^2 (tid<128 = class0 cols)
        float csum = 0.f;
        for (int b = 0; b < nprep; ++b) csum += Cpart[(size_t)b * 256 + tid];
        float sq = csum * csum;
        #pragma unroll
        for (int m = 1; m < 64; m <<= 1) sq += __shfl_xor(sq, m);
        int nv = (tid < nprep) ? n0part[tid] : 0;
        #pragma unroll
        for (int m = 1; m < 64; m <<= 1) nv += __shfl_xor(nv, m);
        float l0 = 0.f, l1 = 0.f;
        for (int i = tid; i < N; i += 256) {
            float d  = S1[i] - E1F;
            float lg = __builtin_amdgcn_logf(d) * LN2;
            if (labels[i] == 0) l0 += lg; else l1 += lg;
        }
        #pragma unroll
        for (int m = 1; m < 64; m <<= 1) { l0 += __shfl_xor(l0, m); l1 += __shfl_xor(l1, m); }

        __shared__ float red[4][3];
        __shared__ int   nred[4];
        if (lane == 0) {
            red[wave][0] = sq; red[wave][1] = l0; red[wave][2] = l1;
            nred[wave] = nv;
        }
        __syncthreads();
        if (tid == 0) {
            float C0sq = (red[0][0] + red[1][0]) * LN2;   // un-scale: SCALE^2 = log2e
            float C1sq = (red[2][0] + red[3][0]) * LN2;
            float L0 = red[0][1] + red[1][1] + red[2][1] + red[3][1];
            float L1 = red[0][2] + red[1][2] + red[2][2] + red[3][2];
            int   n0 = nred[0] + nred[1] + nred[2] + nred[3];
            float fn0 = (float)n0, fn1 = (float)(N - n0);
            float P0 = C0sq - fn0, P1 = C1sq - fn1;
            out[0] = ((fn0 - 1.f) * L0 - P0) / fn0 + (fn1 - 1.f) * L1 - P1;
        }
    }
}

// ---------------------------------------------------------------------------
extern "C" void kernel_launch(void* const* d_in, const int* in_sizes, int n_in,
                              void* d_out, int out_size, void* d_ws, size_t ws_size,
                              hipStream_t stream) {
    (void)n_in; (void)out_size; (void)ws_size;
    const float* X      = (const float*)d_in[0];
    const int*   labels = (const int*)d_in[1];
    int N = in_sizes[1];                       // 8192; assumes D=128, N % 256 == 0
    int nprep = N / 64;                        // 128

    char* ws = (char*)d_ws;
    unsigned short* A       = (unsigned short*)ws;                 // 2 MB
    float*          S1      = (float*)(ws + (size_t)N * D_DIM * 2);         // 32 KB
    float*          Cpart   = (float*)((char*)S1 + (size_t)N * 4);          // nprep*1KB
    int*            n0part  = (int*)((char*)Cpart + (size_t)nprep * 256 * 4);
    int*            counter = n0part + nprep;
    float*          out     = (float*)d_out;

    prep_kernel<<<nprep, 256, 0, stream>>>(X, labels, A, Cpart, n0part, S1, counter);

    dim3 grid(N / 256, NSPLIT);
    main_kernel<<<grid, 256, 0, stream>>>(A, labels, Cpart, n0part, S1, counter, out, N, nprep);
}

// Round 4
// 111.340 us; speedup vs baseline: 1.5817x; 1.5817x over previous
//
#include <hip/hip_runtime.h>

typedef float f32x4 __attribute__((ext_vector_type(4)));
typedef __bf16 bf16x8 __attribute__((ext_vector_type(8)));
typedef unsigned short u16x8 __attribute__((ext_vector_type(8)));

#define D_DIM 128
#define NSPLIT 32
#define SCALE  1.2011224087864498f   // sqrt(log2(e)): both operands scaled -> acc = log2e * sim
#define LN2    0.6931471805599453f
#define E1F    2.7182818284590452f

// fp32 -> bf16 round-to-nearest-even
static __device__ __forceinline__ unsigned short f2bf(float f) {
    unsigned u = __float_as_uint(f);
    u += 0x7fffu + ((u >> 16) & 1u);
    return (unsigned short)(u >> 16);
}

// ---------------------------------------------------------------------------
// prep: L2-normalize rows (scaled by sqrt(log2e)), store bf16 A.
// Accumulate class column-sums into global C[256] (class0: 0..127, class1:
// 128..255) and class-0 count n0. 16-lane groups: 4 rows per wave in parallel.
__global__ __launch_bounds__(256) void prep_kernel(const float* __restrict__ X,
                                                   const int* __restrict__ labels,
                                                   unsigned short* __restrict__ A,
                                                   float* __restrict__ C,
                                                   int* __restrict__ n0) {
    int tid = threadIdx.x, wave = tid >> 6, lane = tid & 63;
    int g = lane >> 4, s = lane & 15;
    int row0 = blockIdx.x * 64;

    float c0[8], c1[8];
    #pragma unroll
    for (int e = 0; e < 8; ++e) { c0[e] = 0.f; c1[e] = 0.f; }

    #pragma unroll
    for (int it = 0; it < 4; ++it) {
        int row = row0 + wave * 16 + it * 4 + g;
        const float4* xp = reinterpret_cast<const float4*>(X + (size_t)row * D_DIM + s * 8);
        float4 xa = xp[0], xb = xp[1];
        float ss = xa.x*xa.x + xa.y*xa.y + xa.z*xa.z + xa.w*xa.w
                 + xb.x*xb.x + xb.y*xb.y + xb.z*xb.z + xb.w*xb.w;
        ss += __shfl_xor(ss, 1); ss += __shfl_xor(ss, 2);
        ss += __shfl_xor(ss, 4); ss += __shfl_xor(ss, 8);
        float rn = rsqrtf(ss) * SCALE;
        float v[8] = { xa.x*rn, xa.y*rn, xa.z*rn, xa.w*rn,
                       xb.x*rn, xb.y*rn, xb.z*rn, xb.w*rn };
        u16x8 o;
        #pragma unroll
        for (int e = 0; e < 8; ++e) o[e] = f2bf(v[e]);
        *reinterpret_cast<u16x8*>(A + (size_t)row * D_DIM + s * 8) = o;
        bool is0 = (labels[row] == 0);
        #pragma unroll
        for (int e = 0; e < 8; ++e) {
            c0[e] += is0 ? v[e] : 0.f;
            c1[e] += is0 ? 0.f : v[e];
        }
    }

    __shared__ float CL[256];
    CL[tid] = 0.f;
    __syncthreads();
    #pragma unroll
    for (int e = 0; e < 8; ++e) {
        atomicAdd(&CL[s * 8 + e],       c0[e]);
        atomicAdd(&CL[128 + s * 8 + e], c1[e]);
    }
    __syncthreads();
    atomicAdd(&C[tid], CL[tid]);

    if (wave == 0) {
        int is0 = (labels[row0 + lane] == 0) ? 1 : 0;
        unsigned long long b = __ballot(is0);
        if (lane == 0) atomicAdd(n0, (int)__popcll(b));
    }
}

// ---------------------------------------------------------------------------
// main: S1part[split][i] = sum_{j in split} exp(sim_ij).
// No LDS, no barriers: each wave owns 64 rows (A-frags in 64 VGPRs) and
// free-runs over its split's 256 cols in 16-col steps, B-frags straight from
// global (L2-resident 2MB), register-double-buffered (bfA/bfB static names).
__global__ __launch_bounds__(256, 3) void main_kernel(const unsigned short* __restrict__ A,
                                                      float* __restrict__ S1part,
                                                      int N) {
    int tid = threadIdx.x, wave = tid >> 6, lane = tid & 63;
    int l15 = lane & 15, lhi = lane >> 4;
    int m0 = blockIdx.x * 256 + wave * 64;
    int split = blockIdx.y;
    int jlen = N / NSPLIT;               // 256
    int j0 = split * jlen;
    int STEPS = jlen / 16;               // 16 (even)

    // A fragments: rows m0 + ms*16 + l15, k = kb*32 + lhi*8 .. +7
    bf16x8 af[4][4];
    const unsigned short* abase = A + (size_t)(m0 + l15) * D_DIM + lhi * 8;
    #pragma unroll
    for (int ms = 0; ms < 4; ++ms)
        #pragma unroll
        for (int kb = 0; kb < 4; ++kb)
            af[ms][kb] = *reinterpret_cast<const bf16x8*>(abase + (size_t)ms * 16 * D_DIM + kb * 32);

    float s1[4][4];
    #pragma unroll
    for (int ms = 0; ms < 4; ++ms)
        #pragma unroll
        for (int r = 0; r < 4; ++r) s1[ms][r] = 0.f;

    const unsigned short* bbase = A + (size_t)(j0 + l15) * D_DIM + lhi * 8;
    bf16x8 bfA[4], bfB[4];
    #pragma unroll
    for (int kb = 0; kb < 4; ++kb)
        bfA[kb] = *reinterpret_cast<const bf16x8*>(bbase + kb * 32);

    for (int t = 0; t < STEPS; t += 2) {
        // prefetch step t+1 while computing step t
        const unsigned short* b1 = bbase + (size_t)(t + 1) * 16 * D_DIM;
        #pragma unroll
        for (int kb = 0; kb < 4; ++kb)
            bfB[kb] = *reinterpret_cast<const bf16x8*>(b1 + kb * 32);
        {
            f32x4 acc[4] = {{0,0,0,0},{0,0,0,0},{0,0,0,0},{0,0,0,0}};
            #pragma unroll
            for (int kb = 0; kb < 4; ++kb)
                #pragma unroll
                for (int ms = 0; ms < 4; ++ms)
                    acc[ms] = __builtin_amdgcn_mfma_f32_16x16x32_bf16(af[ms][kb], bfA[kb], acc[ms], 0, 0, 0);
            #pragma unroll
            for (int ms = 0; ms < 4; ++ms)
                #pragma unroll
                for (int r = 0; r < 4; ++r)
                    s1[ms][r] += __builtin_amdgcn_exp2f(acc[ms][r]);
        }
        // prefetch step t+2 while computing step t+1
        if (t + 2 < STEPS) {
            const unsigned short* b2 = bbase + (size_t)(t + 2) * 16 * D_DIM;
            #pragma unroll
            for (int kb = 0; kb < 4; ++kb)
                bfA[kb] = *reinterpret_cast<const bf16x8*>(b2 + kb * 32);
        }
        {
            f32x4 acc[4] = {{0,0,0,0},{0,0,0,0},{0,0,0,0},{0,0,0,0}};
            #pragma unroll
            for (int kb = 0; kb < 4; ++kb)
                #pragma unroll
                for (int ms = 0; ms < 4; ++ms)
                    acc[ms] = __builtin_amdgcn_mfma_f32_16x16x32_bf16(af[ms][kb], bfB[kb], acc[ms], 0, 0, 0);
            #pragma unroll
            for (int ms = 0; ms < 4; ++ms)
                #pragma unroll
                for (int r = 0; r < 4; ++r)
                    s1[ms][r] += __builtin_amdgcn_exp2f(acc[ms][r]);
        }
    }

    // reduce over the 16 l15-lanes holding the same rows
    #pragma unroll
    for (int m = 1; m < 16; m <<= 1)
        #pragma unroll
        for (int ms = 0; ms < 4; ++ms)
            #pragma unroll
            for (int r = 0; r < 4; ++r)
                s1[ms][r] += __shfl_xor(s1[ms][r], m);
    if (l15 == 0) {
        #pragma unroll
        for (int ms = 0; ms < 4; ++ms)
            #pragma unroll
            for (int r = 0; r < 4; ++r)
                S1part[(size_t)split * N + m0 + ms * 16 + lhi * 4 + r] = s1[ms][r];
    }
}

// ---------------------------------------------------------------------------
// finish: per row S1 = sum of split partials; Lc = sum_{i in c} log(S1_i - e).
// Pos-pair sums via identity: sum_{i in c} sum_{pos j} sim_ij = ||C_c||^2 - n_c.
// Block partials -> scal atomics; last block (counter) computes the loss.
__global__ __launch_bounds__(256) void finish_kernel(const float* __restrict__ S1part,
                                                     const float* __restrict__ C,
                                                     const int* __restrict__ labels,
                                                     int* __restrict__ n0p,
                                                     float* __restrict__ scal,
                                                     int* __restrict__ counter,
                                                     float* __restrict__ out,
                                                     int N) {
    int tid = threadIdx.x, wave = tid >> 6, lane = tid & 63;
    int row = blockIdx.x * 256 + tid;

    float S1 = 0.f;
    for (int s = 0; s < NSPLIT; ++s) S1 += S1part[(size_t)s * N + row];
    bool is0 = (labels[row] == 0);
    float lg = __builtin_amdgcn_logf(S1 - E1F) * LN2;   // natural log of denom
    float v0 = is0 ? lg : 0.f, v1 = is0 ? 0.f : lg;
    #pragma unroll
    for (int m = 1; m < 64; m <<= 1) { v0 += __shfl_xor(v0, m); v1 += __shfl_xor(v1, m); }

    __shared__ float red[4][2];
    __shared__ int isLast;
    if (lane == 0) { red[wave][0] = v0; red[wave][1] = v1; }
    __syncthreads();
    if (tid == 0) {
        atomicAdd(&scal[0], red[0][0] + red[1][0] + red[2][0] + red[3][0]);
        atomicAdd(&scal[1], red[0][1] + red[1][1] + red[2][1] + red[3][1]);
        __threadfence();
        int old = atomicAdd(counter, 1);
        isLast = (old == (int)gridDim.x - 1) ? 1 : 0;
    }
    __syncthreads();
    if (isLast) {
        // tid<128 = class0 columns, tid>=128 = class1 (waves 0,1 vs 2,3)
        float c = C[tid];
        float sq = c * c;
        #pragma unroll
        for (int m = 1; m < 64; m <<= 1) sq += __shfl_xor(sq, m);
        __shared__ float sqred[4];
        if (lane == 0) sqred[wave] = sq;
        __syncthreads();
        if (tid == 0) {
            float C0sq = (sqred[0] + sqred[1]) * LN2;   // un-scale: SCALE^2 = log2e
            float C1sq = (sqred[2] + sqred[3]) * LN2;
            float L0 = atomicAdd(&scal[0], 0.f);
            float L1 = atomicAdd(&scal[1], 0.f);
            int   n0 = atomicAdd(n0p, 0);
            float fn0 = (float)n0, fn1 = (float)(N - n0);
            float P0 = C0sq - fn0, P1 = C1sq - fn1;
            out[0] = ((fn0 - 1.f) * L0 - P0) / fn0 + (fn1 - 1.f) * L1 - P1;
        }
    }
}

// ---------------------------------------------------------------------------
extern "C" void kernel_launch(void* const* d_in, const int* in_sizes, int n_in,
                              void* d_out, int out_size, void* d_ws, size_t ws_size,
                              hipStream_t stream) {
    (void)n_in; (void)out_size; (void)ws_size;
    const float* X      = (const float*)d_in[0];
    const int*   labels = (const int*)d_in[1];
    int N = in_sizes[1];                       // 8192; assumes D=128, N % 256 == 0

    char* ws = (char*)d_ws;
    unsigned short* A       = (unsigned short*)ws;                           // 2 MB
    float*          S1part  = (float*)(ws + (size_t)N * D_DIM * 2);          // 1 MB
    float*          C       = (float*)((char*)S1part + (size_t)NSPLIT * N * 4); // 1 KB
    float*          scal    = (float*)((char*)C + 1024);                     // 8 B
    int*            n0      = (int*)((char*)scal + 8);
    int*            counter = n0 + 1;
    float*          out     = (float*)d_out;

    hipMemsetAsync(C, 0, 1024 + 8 + 4 + 4, stream);

    prep_kernel<<<N / 64, 256, 0, stream>>>(X, labels, A, C, n0);

    dim3 grid(N / 256, NSPLIT);
    main_kernel<<<grid, 256, 0, stream>>>(A, S1part, N);

    finish_kernel<<<N / 256, 256, 0, stream>>>(S1part, C, labels, n0, scal, counter, out, N);
}

// Round 5
// 104.845 us; speedup vs baseline: 1.6797x; 1.0619x over previous
//
#include <hip/hip_runtime.h>

typedef float f32x4 __attribute__((ext_vector_type(4)));
typedef __bf16 bf16x8 __attribute__((ext_vector_type(8)));
typedef unsigned short u16x8 __attribute__((ext_vector_type(8)));

#define D_DIM 128
#define NSPLIT 64
#define SCALE  1.2011224087864498f   // sqrt(log2(e)): both operands scaled -> acc = log2e * sim
#define LN2    0.6931471805599453f
#define E1F    2.7182818284590452f

// fp32 -> bf16 round-to-nearest-even
static __device__ __forceinline__ unsigned short f2bf(float f) {
    unsigned u = __float_as_uint(f);
    u += 0x7fffu + ((u >> 16) & 1u);
    return (unsigned short)(u >> 16);
}

// ---------------------------------------------------------------------------
// prep: normalize rows (scaled by sqrt(log2e)) and store A in MFMA-fragment
// order. Fragment f = jtile*4 + kb is 1 KB: lane l holds row jtile*16+(l&15),
// k = kb*32 + (l>>4)*8 .. +7. Wave w of block b owns jtile = b*4 + w: lane l
// processes row (l&15), k-chunks (l>>4)*8 + kb*32. Row-norm reduce = shfl_xor
// over the 4 lanes sharing (l&15). Also: class column-sums C[256], count n0.
__global__ __launch_bounds__(256) void prep_kernel(const float* __restrict__ X,
                                                   const int* __restrict__ labels,
                                                   unsigned short* __restrict__ P,
                                                   float* __restrict__ C,
                                                   int* __restrict__ n0) {
    int tid = threadIdx.x, wave = tid >> 6, lane = tid & 63;
    int l15 = lane & 15, lhi = lane >> 4;
    int jtile = blockIdx.x * 4 + wave;
    int row = jtile * 16 + l15;

    float v[4][8];
    float ss = 0.f;
    #pragma unroll
    for (int kb = 0; kb < 4; ++kb) {
        const float4* xp = reinterpret_cast<const float4*>(X + (size_t)row * D_DIM + kb * 32 + lhi * 8);
        float4 a = xp[0], b = xp[1];
        v[kb][0] = a.x; v[kb][1] = a.y; v[kb][2] = a.z; v[kb][3] = a.w;
        v[kb][4] = b.x; v[kb][5] = b.y; v[kb][6] = b.z; v[kb][7] = b.w;
        ss += a.x*a.x + a.y*a.y + a.z*a.z + a.w*a.w
            + b.x*b.x + b.y*b.y + b.z*b.z + b.w*b.w;
    }
    ss += __shfl_xor(ss, 16);
    ss += __shfl_xor(ss, 32);
    float rn = rsqrtf(ss) * SCALE;
    bool is0 = (labels[row] == 0);

    #pragma unroll
    for (int kb = 0; kb < 4; ++kb) {
        u16x8 o;
        #pragma unroll
        for (int e = 0; e < 8; ++e) { v[kb][e] *= rn; o[e] = f2bf(v[kb][e]); }
        *reinterpret_cast<u16x8*>(P + ((size_t)jtile * 4 + kb) * 512 + lane * 8) = o;
    }

    // class column-sums via LDS, then one global atomic per slot
    __shared__ float CL[256];
    CL[tid] = 0.f;
    __syncthreads();
    int cbase = is0 ? 0 : 128;
    #pragma unroll
    for (int kb = 0; kb < 4; ++kb)
        #pragma unroll
        for (int e = 0; e < 8; ++e)
            atomicAdd(&CL[cbase + kb * 32 + lhi * 8 + e], v[kb][e]);
    __syncthreads();
    atomicAdd(&C[tid], CL[tid]);

    // class-0 count: one lane per row (lhi==0)
    unsigned long long b = __ballot(is0 && lhi == 0);
    if (lane == 0) atomicAdd(n0, (int)__popcll(b));
}

// ---------------------------------------------------------------------------
// main: S1part[split][i] = sum_{j in split} exp(sim_ij).
// No LDS, no barriers. All loads are packed fragments: P + f*1024B + lane*16B,
// perfectly coalesced. Wave owns 64 rows (af in 64 VGPRs); register-double-
// buffered B fragments (static names bfA/bfB).
__global__ __launch_bounds__(256, 3) void main_kernel(const unsigned short* __restrict__ Pk,
                                                      float* __restrict__ S1part,
                                                      int N) {
    int tid = threadIdx.x, wave = tid >> 6, lane = tid & 63;
    int l15 = lane & 15, lhi = lane >> 4;
    int m0 = blockIdx.x * 256 + wave * 64;
    int split = blockIdx.y;
    int jlen = N / NSPLIT;               // 128
    int j0 = split * jlen;
    const int STEPS = jlen / 16;         // 8 (even)

    const u16x8* P = reinterpret_cast<const u16x8*>(Pk);   // P[f*64 + lane]

    // A fragments: row-tiles m0/16 + ms
    bf16x8 af[4][4];
    int fa0 = (m0 >> 4) * 4;
    #pragma unroll
    for (int ms = 0; ms < 4; ++ms)
        #pragma unroll
        for (int kb = 0; kb < 4; ++kb)
            af[ms][kb] = __builtin_bit_cast(bf16x8, P[(size_t)(fa0 + ms * 4 + kb) * 64 + lane]);

    float s1[4][4];
    #pragma unroll
    for (int ms = 0; ms < 4; ++ms)
        #pragma unroll
        for (int r = 0; r < 4; ++r) s1[ms][r] = 0.f;

    int t0 = (j0 >> 4);                  // first j-tile index
    bf16x8 bfA[4], bfB[4];
    #pragma unroll
    for (int kb = 0; kb < 4; ++kb)
        bfA[kb] = __builtin_bit_cast(bf16x8, P[(size_t)(t0 * 4 + kb) * 64 + lane]);

    for (int t = 0; t < STEPS; t += 2) {
        // prefetch tile t+1 while computing tile t
        #pragma unroll
        for (int kb = 0; kb < 4; ++kb)
            bfB[kb] = __builtin_bit_cast(bf16x8, P[(size_t)((t0 + t + 1) * 4 + kb) * 64 + lane]);
        {
            f32x4 acc[4] = {{0,0,0,0},{0,0,0,0},{0,0,0,0},{0,0,0,0}};
            #pragma unroll
            for (int kb = 0; kb < 4; ++kb)
                #pragma unroll
                for (int ms = 0; ms < 4; ++ms)
                    acc[ms] = __builtin_amdgcn_mfma_f32_16x16x32_bf16(af[ms][kb], bfA[kb], acc[ms], 0, 0, 0);
            #pragma unroll
            for (int ms = 0; ms < 4; ++ms)
                #pragma unroll
                for (int r = 0; r < 4; ++r)
                    s1[ms][r] += __builtin_amdgcn_exp2f(acc[ms][r]);
        }
        // prefetch tile t+2 while computing tile t+1
        if (t + 2 < STEPS) {
            #pragma unroll
            for (int kb = 0; kb < 4; ++kb)
                bfA[kb] = __builtin_bit_cast(bf16x8, P[(size_t)((t0 + t + 2) * 4 + kb) * 64 + lane]);
        }
        {
            f32x4 acc[4] = {{0,0,0,0},{0,0,0,0},{0,0,0,0},{0,0,0,0}};
            #pragma unroll
            for (int kb = 0; kb < 4; ++kb)
                #pragma unroll
                for (int ms = 0; ms < 4; ++ms)
                    acc[ms] = __builtin_amdgcn_mfma_f32_16x16x32_bf16(af[ms][kb], bfB[kb], acc[ms], 0, 0, 0);
            #pragma unroll
            for (int ms = 0; ms < 4; ++ms)
                #pragma unroll
                for (int r = 0; r < 4; ++r)
                    s1[ms][r] += __builtin_amdgcn_exp2f(acc[ms][r]);
        }
    }

    // reduce over the 16 l15-lanes holding the same rows
    #pragma unroll
    for (int m = 1; m < 16; m <<= 1)
        #pragma unroll
        for (int ms = 0; ms < 4; ++ms)
            #pragma unroll
            for (int r = 0; r < 4; ++r)
                s1[ms][r] += __shfl_xor(s1[ms][r], m);
    if (l15 == 0) {
        #pragma unroll
        for (int ms = 0; ms < 4; ++ms)
            #pragma unroll
            for (int r = 0; r < 4; ++r)
                S1part[(size_t)split * N + m0 + ms * 16 + lhi * 4 + r] = s1[ms][r];
    }
}

// ---------------------------------------------------------------------------
// finish: per row S1 = sum of split partials; Lc = sum_{i in c} log(S1_i - e).
// Pos-pair sums via identity: sum_{i in c} sum_{pos j} sim_ij = ||C_c||^2 - n_c.
// Block partials -> scal atomics; last block (counter) computes the loss.
__global__ __launch_bounds__(256) void finish_kernel(const float* __restrict__ S1part,
                                                     const float* __restrict__ C,
                                                     const int* __restrict__ labels,
                                                     int* __restrict__ n0p,
                                                     float* __restrict__ scal,
                                                     int* __restrict__ counter,
                                                     float* __restrict__ out,
                                                     int N) {
    int tid = threadIdx.x, wave = tid >> 6, lane = tid & 63;
    int row = blockIdx.x * 256 + tid;

    float S1 = 0.f;
    for (int s = 0; s < NSPLIT; ++s) S1 += S1part[(size_t)s * N + row];
    bool is0 = (labels[row] == 0);
    float lg = __builtin_amdgcn_logf(S1 - E1F) * LN2;   // natural log of denom
    float v0 = is0 ? lg : 0.f, v1 = is0 ? 0.f : lg;
    #pragma unroll
    for (int m = 1; m < 64; m <<= 1) { v0 += __shfl_xor(v0, m); v1 += __shfl_xor(v1, m); }

    __shared__ float red[4][2];
    __shared__ int isLast;
    if (lane == 0) { red[wave][0] = v0; red[wave][1] = v1; }
    __syncthreads();
    if (tid == 0) {
        atomicAdd(&scal[0], red[0][0] + red[1][0] + red[2][0] + red[3][0]);
        atomicAdd(&scal[1], red[0][1] + red[1][1] + red[2][1] + red[3][1]);
        __threadfence();
        int old = atomicAdd(counter, 1);
        isLast = (old == (int)gridDim.x - 1) ? 1 : 0;
    }
    __syncthreads();
    if (isLast) {
        // tid<128 = class0 columns, tid>=128 = class1 (waves 0,1 vs 2,3)
        float c = C[tid];
        float sq = c * c;
        #pragma unroll
        for (int m = 1; m < 64; m <<= 1) sq += __shfl_xor(sq, m);
        __shared__ float sqred[4];
        if (lane == 0) sqred[wave] = sq;
        __syncthreads();
        if (tid == 0) {
            float C0sq = (sqred[0] + sqred[1]) * LN2;   // un-scale: SCALE^2 = log2e
            float C1sq = (sqred[2] + sqred[3]) * LN2;
            float L0 = atomicAdd(&scal[0], 0.f);
            float L1 = atomicAdd(&scal[1], 0.f);
            int   n0 = atomicAdd(n0p, 0);
            float fn0 = (float)n0, fn1 = (float)(N - n0);
            float P0 = C0sq - fn0, P1 = C1sq - fn1;
            out[0] = ((fn0 - 1.f) * L0 - P0) / fn0 + (fn1 - 1.f) * L1 - P1;
        }
    }
}

// ---------------------------------------------------------------------------
extern "C" void kernel_launch(void* const* d_in, const int* in_sizes, int n_in,
                              void* d_out, int out_size, void* d_ws, size_t ws_size,
                              hipStream_t stream) {
    (void)n_in; (void)out_size; (void)ws_size;
    const float* X      = (const float*)d_in[0];
    const int*   labels = (const int*)d_in[1];
    int N = in_sizes[1];                       // 8192; assumes D=128, N % 256 == 0

    char* ws = (char*)d_ws;
    unsigned short* A_pack  = (unsigned short*)ws;                              // 2 MB
    float*          S1part  = (float*)(ws + (size_t)N * D_DIM * 2);             // 2 MB
    float*          C       = (float*)((char*)S1part + (size_t)NSPLIT * N * 4); // 1 KB
    float*          scal    = (float*)((char*)C + 1024);                        // 8 B
    int*            n0      = (int*)((char*)scal + 8);
    int*            counter = n0 + 1;
    float*          out     = (float*)d_out;

    hipMemsetAsync(C, 0, 1024 + 8 + 4 + 4, stream);

    prep_kernel<<<N / 64, 256, 0, stream>>>(X, labels, A_pack, C, n0);

    dim3 grid(N / 256, NSPLIT);
    main_kernel<<<grid, 256, 0, stream>>>(A_pack, S1part, N);

    finish_kernel<<<N / 256, 256, 0, stream>>>(S1part, C, labels, n0, scal, counter, out, N);
}